// Round 3
// baseline (326.788 us; speedup 1.0000x reference)
//
#include <hip/hip_runtime.h>

#define NTOK   8192
#define DMODEL 1024
#define NC     64
#define NK     16
#define NP     64
#define NM     128
#define LCAP   (1 << 18)
#define MARGIN 0.045f

typedef _Float16 f16x8 __attribute__((ext_vector_type(8)));
typedef float    f32x4 __attribute__((ext_vector_type(4)));

#define AS1 __attribute__((address_space(1)))
#define AS3 __attribute__((address_space(3)))

__device__ __forceinline__ void glds16(const void* g, void* l) {
    __builtin_amdgcn_global_load_lds((const AS1 void*)g, (AS3 void*)l, 16, 0, 0);
}

// ------------------------------------------------------------------
// Kernel 0: convert x, W_A, W_B to fp16 with subtiled layout
// [k/8][row][8] so the GEMM can stage via linear global_load_lds.
// ------------------------------------------------------------------
__global__ __launch_bounds__(256) void k_split(
    const float* __restrict__ x, const float* __restrict__ W_A, const float* __restrict__ W_B,
    short* __restrict__ xh, short* __restrict__ whA, short* __restrict__ whB)
{
    const int t = blockIdx.x * 256 + threadIdx.x;
    const int NX = 128 * NTOK;            // 1048576 units
    const int NW = 128 * 1024;            // 131072 units

    const float* src;
    short* dh;
    if (t < NX) {
        const int chunk = t >> 13, tok = t & 8191;
        src = x + (size_t)tok * DMODEL + chunk * 8;
        dh = xh + (size_t)t * 8;
    } else if (t < NX + NW) {
        const int u = t - NX, chunk = u >> 10, ck = u & 1023;
        src = W_A + (size_t)ck * DMODEL + chunk * 8;
        dh = whA + (size_t)u * 8;
    } else {
        const int u = t - NX - NW, chunk = u >> 10, ck = u & 1023;
        src = W_B + (size_t)ck * DMODEL + chunk * 8;
        dh = whB + (size_t)u * 8;
    }

    const float4 a = *(const float4*)src;
    const float4 b = *(const float4*)(src + 4);
    const float v[8] = {a.x, a.y, a.z, a.w, b.x, b.y, b.z, b.w};
    unsigned h[8];
    #pragma unroll
    for (int j = 0; j < 8; ++j)
        h[j] = (unsigned)__builtin_bit_cast(unsigned short, (_Float16)v[j]);
    *(int4*)dh = make_int4((int)(h[0] | (h[1] << 16)), (int)(h[2] | (h[3] << 16)),
                           (int)(h[4] | (h[5] << 16)), (int)(h[6] | (h[7] << 16)));
}

// ------------------------------------------------------------------
// Kernel 1: fp16 MFMA GEMM (proj = x @ W^T) fused with d2 + argmin.
// Tile 128 tok x 128 ck, BK=64 double-buffered, 4 waves, 16x16x32 MFMA.
// Near-ties (gap < MARGIN ~ 11 sigma of fp16 error) -> fp64 refine list.
// ------------------------------------------------------------------
__global__ __launch_bounds__(256, 2) void k_mfma_argmin(
    const short* __restrict__ xh, const short* __restrict__ whA, const short* __restrict__ whB,
    const float* __restrict__ emb_A, const float* __restrict__ emb_B,
    int* __restrict__ idxbuf, int* __restrict__ list, int* __restrict__ cnt)
{
    __shared__ __align__(16) float smem[16384];   // 64 KB
    short* ls = (short*)smem;
    // GEMM dbuf: buf b at units [b*2048, b*2048+1024) = A, [+1024, +2048) = B
    float* proj = smem;                    // epilogue: [64][132]
    float* embS = smem + 8448;             // [4][1032]
    float* e2S  = smem + 12576;            // [256]

    const int tid = threadIdx.x;
    const int tb  = blockIdx.x;            // token block 0..63
    const int ot  = blockIdx.y;            // out tile 0..15
    const int set = ot >> 3;
    const short* __restrict__ wh = set ? whB : whA;
    const float* __restrict__ Ep = set ? emb_B : emb_A;
    const int cbase = (ot & 7) * 8;

    const int lane = tid & 63;
    const int wid  = tid >> 6;
    const int wr   = wid >> 1;             // token half 0..1
    const int wc   = wid & 1;              // ck half 0..1
    const int lrow = lane & 15;
    const int lk   = lane >> 4;

    f32x4 acc[4][4];
    #pragma unroll
    for (int m = 0; m < 4; ++m)
        #pragma unroll
        for (int n = 0; n < 4; ++n) acc[m][n] = (f32x4){0.f, 0.f, 0.f, 0.f};

    #define STAGE(buf, k0c)                                                             \
        do {                                                                            \
            _Pragma("unroll")                                                           \
            for (int i_ = 0; i_ < 4; ++i_) {                                            \
                const int u_ = i_ * 256 + tid;                                          \
                const int ch_ = u_ >> 7, r_ = u_ & 127;                                 \
                glds16(xh + ((size_t)((k0c) + ch_) * NTOK + tb * 128 + r_) * 8,         \
                       ls + (size_t)((buf) * 2048 + u_) * 8);                           \
                glds16(wh + ((size_t)((k0c) + ch_) * 1024 + cbase * 16 + r_) * 8,       \
                       ls + (size_t)((buf) * 2048 + 1024 + u_) * 8);                    \
            }                                                                           \
        } while (0)

    STAGE(0, 0);
    __syncthreads();
    int cur = 0;
    for (int step = 0; step < 16; ++step) {
        if (step < 15) STAGE(cur ^ 1, (step + 1) * 8);
        const int cb = cur * 2048;
        #pragma unroll
        for (int ks = 0; ks < 2; ++ks) {
            const int cofs = ks * 4 + lk;
            f16x8 a[4], b[4];
            #pragma unroll
            for (int m = 0; m < 4; ++m) {
                a[m] = *(const f16x8*)(ls + (size_t)(cb + cofs * 128 + wr * 64 + m * 16 + lrow) * 8);
                b[m] = *(const f16x8*)(ls + (size_t)(cb + 1024 + cofs * 128 + wc * 64 + m * 16 + lrow) * 8);
            }
            #pragma unroll
            for (int m = 0; m < 4; ++m)
                #pragma unroll
                for (int n = 0; n < 4; ++n)
                    acc[m][n] = __builtin_amdgcn_mfma_f32_16x16x32_f16(a[m], b[n], acc[m][n], 0, 0, 0);
        }
        __syncthreads();
        cur ^= 1;
    }
    #undef STAGE

    // ---- epilogue: d2 + argmin, two token halves x two codebook halves ----
    for (int h = 0; h < 2; ++h) {
        __syncthreads();
        if (wr == h) {
            #pragma unroll
            for (int m = 0; m < 4; ++m)
                #pragma unroll
                for (int n = 0; n < 4; ++n)
                    #pragma unroll
                    for (int r = 0; r < 4; ++r)
                        proj[(m * 16 + lk * 4 + r) * 132 + wc * 64 + n * 16 + lrow] = acc[m][n][r];
        }
        for (int ch = 0; ch < 2; ++ch) {
            __syncthreads();
            {   // stage 4 codebooks of emb, per-codebook stride 1032 (bank-spread)
                const float4* eg = (const float4*)(Ep + (size_t)(cbase + ch * 4) * NP * NK);
                #pragma unroll
                for (int i = 0; i < 4; ++i) {
                    const int idx = tid + 256 * i;        // 0..1023 float4 units
                    const int cb4 = idx >> 8, win = idx & 255;
                    ((float4*)(embS + cb4 * 1032))[win] = eg[idx];
                }
            }
            __syncthreads();
            {   // e2 per (c_local, p)
                const float* e = embS + (tid >> 6) * 1032 + (tid & 63) * 16;
                float s = 0.f;
                #pragma unroll
                for (int k = 0; k < 16; ++k) s = fmaf(e[k], e[k], s);
                e2S[tid] = s;
            }
            __syncthreads();
            {
                const int cl = tid >> 6, lt = tid & 63;
                float pr[16];
                const float4* pp = (const float4*)(proj + lt * 132 + (ch * 4 + cl) * 16);
                #pragma unroll
                for (int q = 0; q < 4; ++q) {
                    const float4 v = pp[q];
                    pr[q * 4 + 0] = v.x; pr[q * 4 + 1] = v.y;
                    pr[q * 4 + 2] = v.z; pr[q * 4 + 3] = v.w;
                }
                const float4* eb4 = (const float4*)(embS + cl * 1032);
                const float* e2 = e2S + cl * 64;
                float best = 1e30f, second = 1e30f;
                int bp = 0;
                for (int p = 0; p < 64; ++p) {
                    const float4 e0 = eb4[p * 4 + 0], e1 = eb4[p * 4 + 1];
                    const float4 e2v = eb4[p * 4 + 2], e3 = eb4[p * 4 + 3];
                    float s = 0.f;
                    s = fmaf(pr[0], e0.x, s);  s = fmaf(pr[1], e0.y, s);
                    s = fmaf(pr[2], e0.z, s);  s = fmaf(pr[3], e0.w, s);
                    s = fmaf(pr[4], e1.x, s);  s = fmaf(pr[5], e1.y, s);
                    s = fmaf(pr[6], e1.z, s);  s = fmaf(pr[7], e1.w, s);
                    s = fmaf(pr[8], e2v.x, s); s = fmaf(pr[9], e2v.y, s);
                    s = fmaf(pr[10], e2v.z, s); s = fmaf(pr[11], e2v.w, s);
                    s = fmaf(pr[12], e3.x, s); s = fmaf(pr[13], e3.y, s);
                    s = fmaf(pr[14], e3.z, s); s = fmaf(pr[15], e3.w, s);
                    const float g = fmaf(-2.f, s, e2[p]);
                    if (g < best) { second = best; best = g; bp = p; }
                    else if (g < second) { second = g; }
                }
                const int c = cbase + ch * 4 + cl;
                const int gtok = tb * 128 + h * 64 + lt;
                idxbuf[(set * NC + c) * NTOK + gtok] = bp;
                if (second - best < MARGIN) {
                    const int slot = atomicAdd(cnt, 1);
                    if (slot < LCAP) list[slot] = (set << 19) | (c << 13) | gtok;
                }
            }
        }
    }
}

// ------------------------------------------------------------------
// Kernel 2: fp64 exact re-resolution of flagged near-tie argmins.
// ------------------------------------------------------------------
__global__ __launch_bounds__(256) void k_refine(
    const float* __restrict__ x,
    const float* __restrict__ W_A, const float* __restrict__ W_B,
    const float* __restrict__ emb_A, const float* __restrict__ emb_B,
    const int* __restrict__ list, const int* __restrict__ cnt,
    int* __restrict__ idxbuf)
{
    int n = *cnt;
    if (n > LCAP) n = LCAP;
    const int lane = threadIdx.x & 63;
    const int wave = (int)((blockIdx.x * blockDim.x + threadIdx.x) >> 6);
    const int nw   = (int)((gridDim.x * blockDim.x) >> 6);

    for (int i = wave; i < n; i += nw) {
        const int code = list[i];
        const int tok = code & 8191;
        const int c   = (code >> 13) & 63;
        const int set = (code >> 19) & 1;
        const float* __restrict__ Wp = set ? W_B : W_A;
        const float* __restrict__ Ep = set ? emb_B : emb_A;

        double pk[16];
        #pragma unroll
        for (int k = 0; k < 16; ++k) pk[k] = 0.0;
        for (int dd = 0; dd < 16; ++dd) {
            const int d = dd * 64 + lane;
            const double xv = (double)x[(size_t)tok * DMODEL + d];
            #pragma unroll
            for (int k = 0; k < 16; ++k)
                pk[k] = fma(xv, (double)Wp[(size_t)(c * 16 + k) * DMODEL + d], pk[k]);
        }
        #pragma unroll
        for (int k = 0; k < 16; ++k) {
            #pragma unroll
            for (int off = 32; off; off >>= 1)
                pk[k] += __shfl_xor(pk[k], off, 64);
        }
        double d2 = 0.0;
        #pragma unroll
        for (int k = 0; k < 16; ++k) {
            const double t = pk[k] - (double)Ep[(size_t)(c * NP + lane) * NK + k];
            d2 = fma(t, t, d2);
        }
        int bp = lane;
        double bv = d2;
        #pragma unroll
        for (int off = 32; off; off >>= 1) {
            const double ov = __shfl_xor(bv, off, 64);
            const int    op = __shfl_xor(bp, off, 64);
            if (ov < bv || (ov == bv && op < bp)) { bv = ov; bp = op; }
        }
        if (lane == 0) idxbuf[(set * NC + c) * NTOK + tok] = bp;
    }
}

// ------------------------------------------------------------------
// Kernel 3: per-token gather + t[r] + out[d]. One block per token.
// ------------------------------------------------------------------
__global__ __launch_bounds__(256) void k_combine(
    const float* __restrict__ x,
    const float* __restrict__ vals_A, const float* __restrict__ vals_B,
    const int* __restrict__ idxbuf, float* __restrict__ out)
{
    __shared__ float xsh[1032];
    __shared__ float part[256];
    __shared__ float tsh[8];
    __shared__ int sIA[64];
    __shared__ int sIB[64];

    const int tid = threadIdx.x;
    const int tok = blockIdx.x;

    if (tid < 64) {
        sIA[tid] = idxbuf[tid * NTOK + tok];
        sIB[tid] = idxbuf[(NC + tid) * NTOK + tok];
    }
    {
        const float4 v = *(const float4*)(x + (size_t)tok * DMODEL + tid * 4);
        const int base = tid * 4 + (tid >> 5);
        xsh[base + 0] = v.x;
        xsh[base + 1] = v.y;
        xsh[base + 2] = v.z;
        xsh[base + 3] = v.w;
    }
    __syncthreads();
    {
        const int c = tid & 63, mseg = tid >> 6;
        const int ia = sIA[c];
        const float4* va = (const float4*)(vals_A + (size_t)(c * NP + ia) * NM + mseg * 32);
        const float* xb = xsh + (c & 7) * 129 + mseg * 32;
        float s = 0.f;
        #pragma unroll
        for (int i = 0; i < 8; ++i) {
            const float4 v = va[i];
            s = fmaf(v.x, xb[i * 4 + 0], s);
            s = fmaf(v.y, xb[i * 4 + 1], s);
            s = fmaf(v.z, xb[i * 4 + 2], s);
            s = fmaf(v.w, xb[i * 4 + 3], s);
        }
        part[tid] = s;
    }
    __syncthreads();
    if (tid < 8) {
        float s = 0.f;
        #pragma unroll
        for (int m = 0; m < 4; ++m)
            #pragma unroll
            for (int j = 0; j < 8; ++j)
                s += part[m * 64 + tid * 8 + j];
        tsh[tid] = s;
    }
    __syncthreads();
    {
        const int d0 = tid * 4, dblk = tid >> 5, dm = d0 & 127;
        float o0 = 0.f, o1 = 0.f, o2 = 0.f, o3 = 0.f;
        #pragma unroll
        for (int r = 0; r < 8; ++r) {
            const int cb = 8 * r + dblk;
            const int ib = sIB[cb];
            const float4 v = *(const float4*)(vals_B + (size_t)(cb * NP + ib) * NM + dm);
            const float tv = tsh[r];
            o0 = fmaf(tv, v.x, o0);
            o1 = fmaf(tv, v.y, o1);
            o2 = fmaf(tv, v.z, o2);
            o3 = fmaf(tv, v.w, o3);
        }
        *(float4*)(out + (size_t)tok * DMODEL + d0) = make_float4(o0, o1, o2, o3);
    }
}

extern "C" void kernel_launch(void* const* d_in, const int* in_sizes, int n_in,
                              void* d_out, int out_size, void* d_ws, size_t ws_size,
                              hipStream_t stream)
{
    const float* x      = (const float*)d_in[0];
    const float* W_A    = (const float*)d_in[1];
    const float* emb_A  = (const float*)d_in[2];
    const float* vals_A = (const float*)d_in[3];
    const float* W_B    = (const float*)d_in[4];
    const float* emb_B  = (const float*)d_in[5];
    const float* vals_B = (const float*)d_in[6];
    float* out = (float*)d_out;

    // ws layout (bytes): cnt 16 | list 1MB | idxbuf 4MB | xh 16MB | whA 4MB | whB 4MB
    char* w = (char*)d_ws;
    int*   cnt    = (int*)w;
    int*   list   = (int*)(w + 16);
    int*   idxbuf = (int*)(w + 16 + sizeof(int) * (size_t)LCAP);
    size_t off = 16 + sizeof(int) * (size_t)LCAP + sizeof(int) * (size_t)(2 * NC * NTOK);
    short* xh  = (short*)(w + off); off += (size_t)NTOK * DMODEL * 2;
    short* whA = (short*)(w + off); off += (size_t)1024 * DMODEL * 2;
    short* whB = (short*)(w + off);

    hipMemsetAsync(cnt, 0, sizeof(int), stream);
    k_split<<<5120, 256, 0, stream>>>(x, W_A, W_B, xh, whA, whB);
    k_mfma_argmin<<<dim3(64, 16), 256, 0, stream>>>(xh, whA, whB,
                                                    emb_A, emb_B, idxbuf, list, cnt);
    k_refine<<<1024, 256, 0, stream>>>(x, W_A, W_B, emb_A, emb_B, list, cnt, idxbuf);
    k_combine<<<NTOK, 256, 0, stream>>>(x, vals_A, vals_B, idxbuf, out);
}

// Round 4
// 234.354 us; speedup vs baseline: 1.3944x; 1.3944x over previous
//
#include <hip/hip_runtime.h>

#define NTOK   8192
#define DMODEL 1024
#define NC     64
#define NK     16
#define NP     64
#define NM     128
#define LCAP   (1 << 18)
#define MARGIN 2e-3f

typedef _Float16 f16x8 __attribute__((ext_vector_type(8)));
typedef float    f32x4 __attribute__((ext_vector_type(4)));

#define AS1 __attribute__((address_space(1)))
#define AS3 __attribute__((address_space(3)))

__device__ __forceinline__ void glds16(const void* g, void* l) {
    __builtin_amdgcn_global_load_lds((const AS1 void*)g, (AS3 void*)l, 16, 0, 0);
}

// ------------------------------------------------------------------
// Kernel 0: split x, W_A, W_B into fp16 hi/lo with subtiled layout
// [k/8][row][8] so the GEMM stages via linear global_load_lds.
// hi = f16(v), lo = f16(v - hi): combined ~22-bit mantissa.
// ------------------------------------------------------------------
__global__ __launch_bounds__(256) void k_split(
    const float* __restrict__ x, const float* __restrict__ W_A, const float* __restrict__ W_B,
    short* __restrict__ xh, short* __restrict__ xl,
    short* __restrict__ whA, short* __restrict__ wlA,
    short* __restrict__ whB, short* __restrict__ wlB)
{
    const int t = blockIdx.x * 256 + threadIdx.x;
    const int NX = 128 * NTOK;            // 1048576 units
    const int NW = 128 * 1024;            // 131072 units

    const float* src;
    short *dh, *dl;
    if (t < NX) {
        const int chunk = t >> 13, tok = t & 8191;
        src = x + (size_t)tok * DMODEL + chunk * 8;
        dh = xh + (size_t)t * 8;  dl = xl + (size_t)t * 8;
    } else if (t < NX + NW) {
        const int u = t - NX, chunk = u >> 10, ck = u & 1023;
        src = W_A + (size_t)ck * DMODEL + chunk * 8;
        dh = whA + (size_t)u * 8; dl = wlA + (size_t)u * 8;
    } else {
        const int u = t - NX - NW, chunk = u >> 10, ck = u & 1023;
        src = W_B + (size_t)ck * DMODEL + chunk * 8;
        dh = whB + (size_t)u * 8; dl = wlB + (size_t)u * 8;
    }

    const float4 a = *(const float4*)src;
    const float4 b = *(const float4*)(src + 4);
    const float v[8] = {a.x, a.y, a.z, a.w, b.x, b.y, b.z, b.w};
    unsigned h[8], l[8];
    #pragma unroll
    for (int j = 0; j < 8; ++j) {
        const _Float16 hf = (_Float16)v[j];
        const _Float16 lf = (_Float16)(v[j] - (float)hf);
        h[j] = (unsigned)__builtin_bit_cast(unsigned short, hf);
        l[j] = (unsigned)__builtin_bit_cast(unsigned short, lf);
    }
    *(int4*)dh = make_int4((int)(h[0] | (h[1] << 16)), (int)(h[2] | (h[3] << 16)),
                           (int)(h[4] | (h[5] << 16)), (int)(h[6] | (h[7] << 16)));
    *(int4*)dl = make_int4((int)(l[0] | (l[1] << 16)), (int)(l[2] | (l[3] << 16)),
                           (int)(l[4] | (l[5] << 16)), (int)(l[6] | (l[7] << 16)));
}

// ------------------------------------------------------------------
// Kernel 1: fp16x3 MFMA GEMM (xh*wh + xh*wl + xl*wh) + d2 + argmin.
// Tile 128 tok x 128 ck, BK=32, double-buffered (2 x 32 KB), 4 waves.
// Counted-vmcnt pipeline: STAGE(next); vmcnt(8); barrier; compute;
// barrier  -> prefetch latency hides under a full compute phase.
// ------------------------------------------------------------------
__global__ __launch_bounds__(256, 2) void k_mfma_argmin(
    const short* __restrict__ xh, const short* __restrict__ xl,
    const short* __restrict__ whA, const short* __restrict__ wlA,
    const short* __restrict__ whB, const short* __restrict__ wlB,
    const float* __restrict__ emb_A, const float* __restrict__ emb_B,
    int* __restrict__ idxbuf, int* __restrict__ list, int* __restrict__ cnt)
{
    __shared__ __align__(16) float smem[16384];   // 64 KB
    short* ls = (short*)smem;
    // buf b (shorts): ah at b*16384+0, al +4096, bh +8192, bl +12288
    float* proj = smem;                    // epilogue: [64][132]
    float* embS = smem + 8448;             // [4][1032]
    float* e2S  = smem + 12576;            // [256]

    const int tid = threadIdx.x;
    // XCD-chunked swizzle: 1024 blocks, xcd = bid&7 owns contiguous 128;
    // within a chunk: ot fastest (all XCDs sweep W in sync; x-tile L2-hot).
    const int bid = blockIdx.x;
    const int swz = (bid & 7) * 128 + (bid >> 3);
    const int tb  = swz >> 4;              // token block 0..63
    const int ot  = swz & 15;              // out tile 0..15
    const int set = ot >> 3;
    const short* __restrict__ wh = set ? whB : whA;
    const short* __restrict__ wl = set ? wlB : wlA;
    const float* __restrict__ Ep = set ? emb_B : emb_A;
    const int cbase = (ot & 7) * 8;

    const int lane = tid & 63;
    const int wid  = tid >> 6;
    const int wr   = wid >> 1;             // token half 0..1
    const int wc   = wid & 1;              // ck half 0..1
    const int lrow = lane & 15;
    const int lk   = lane >> 4;

    f32x4 acc[4][4];
    #pragma unroll
    for (int m = 0; m < 4; ++m)
        #pragma unroll
        for (int n = 0; n < 4; ++n) acc[m][n] = (f32x4){0.f, 0.f, 0.f, 0.f};

    // per-thread global staging pointers (chunk-strided per step)
    const int r7 = tid >> 7, r127 = tid & 127;
    const short* gA0 = xh + ((size_t)r7 * NTOK + tb * 128 + r127) * 8;
    const short* gA1 = xl + ((size_t)r7 * NTOK + tb * 128 + r127) * 8;
    const short* gB0 = wh + ((size_t)r7 * 1024 + cbase * 16 + r127) * 8;
    const short* gB1 = wl + ((size_t)r7 * 1024 + cbase * 16 + r127) * 8;

    #define STAGE(buf, st)                                                   \
        do {                                                                 \
            const size_t sa_ = (size_t)(st) * (4 * NTOK * 8);                \
            const size_t sb_ = (size_t)(st) * (4 * 1024 * 8);                \
            short* lb_ = ls + (buf) * 16384 + tid * 8;                       \
            glds16(gA0 + sa_,                lb_);                           \
            glds16(gA0 + sa_ + 2 * NTOK * 8, lb_ + 2048);                    \
            glds16(gA1 + sa_,                lb_ + 4096);                    \
            glds16(gA1 + sa_ + 2 * NTOK * 8, lb_ + 6144);                    \
            glds16(gB0 + sb_,                lb_ + 8192);                    \
            glds16(gB0 + sb_ + 2 * 1024 * 8, lb_ + 10240);                   \
            glds16(gB1 + sb_,                lb_ + 12288);                   \
            glds16(gB1 + sb_ + 2 * 1024 * 8, lb_ + 14336);                   \
        } while (0)

    const int fa = (lk * 128 + wr * 64 + lrow) * 8;
    const int fb = 8192 + (lk * 128 + wc * 64 + lrow) * 8;

    STAGE(0, 0);
    for (int t = 0; t < 32; ++t) {
        const int cur = t & 1;
        if (t < 31) {
            STAGE(cur ^ 1, t + 1);
            asm volatile("s_waitcnt vmcnt(8)" ::: "memory");
        } else {
            asm volatile("s_waitcnt vmcnt(0)" ::: "memory");
        }
        __builtin_amdgcn_sched_barrier(0);
        __builtin_amdgcn_s_barrier();

        const short* pa = ls + cur * 16384 + fa;
        const short* pb = ls + cur * 16384 + fb;
        f16x8 ah[4], al[4], bh[4], bl[4];
        #pragma unroll
        for (int m = 0; m < 4; ++m) {
            ah[m] = *(const f16x8*)(pa + m * 128);
            al[m] = *(const f16x8*)(pa + 4096 + m * 128);
            bh[m] = *(const f16x8*)(pb + m * 128);
            bl[m] = *(const f16x8*)(pb + 4096 + m * 128);
        }
        #pragma unroll
        for (int m = 0; m < 4; ++m)
            #pragma unroll
            for (int n = 0; n < 4; ++n) {
                acc[m][n] = __builtin_amdgcn_mfma_f32_16x16x32_f16(ah[m], bh[n], acc[m][n], 0, 0, 0);
                acc[m][n] = __builtin_amdgcn_mfma_f32_16x16x32_f16(ah[m], bl[n], acc[m][n], 0, 0, 0);
                acc[m][n] = __builtin_amdgcn_mfma_f32_16x16x32_f16(al[m], bh[n], acc[m][n], 0, 0, 0);
            }
        __builtin_amdgcn_s_barrier();
    }
    #undef STAGE

    // ---- epilogue: d2 + argmin, two token halves x two codebook halves ----
    for (int h = 0; h < 2; ++h) {
        __syncthreads();
        if (wr == h) {
            #pragma unroll
            for (int m = 0; m < 4; ++m)
                #pragma unroll
                for (int n = 0; n < 4; ++n)
                    #pragma unroll
                    for (int r = 0; r < 4; ++r)
                        proj[(m * 16 + lk * 4 + r) * 132 + wc * 64 + n * 16 + lrow] = acc[m][n][r];
        }
        for (int ch = 0; ch < 2; ++ch) {
            __syncthreads();
            {   // stage 4 codebooks of emb, per-codebook stride 1032
                const float4* eg = (const float4*)(Ep + (size_t)(cbase + ch * 4) * NP * NK);
                #pragma unroll
                for (int i = 0; i < 4; ++i) {
                    const int idx = tid + 256 * i;
                    const int cb4 = idx >> 8, win = idx & 255;
                    ((float4*)(embS + cb4 * 1032))[win] = eg[idx];
                }
            }
            __syncthreads();
            {   // e2 per (c_local, p)
                const float* e = embS + (tid >> 6) * 1032 + (tid & 63) * 16;
                float s = 0.f;
                #pragma unroll
                for (int k = 0; k < 16; ++k) s = fmaf(e[k], e[k], s);
                e2S[tid] = s;
            }
            __syncthreads();
            {
                const int cl = tid >> 6, lt = tid & 63;
                float pr[16];
                const float4* pp = (const float4*)(proj + lt * 132 + (ch * 4 + cl) * 16);
                #pragma unroll
                for (int q = 0; q < 4; ++q) {
                    const float4 v = pp[q];
                    pr[q * 4 + 0] = v.x; pr[q * 4 + 1] = v.y;
                    pr[q * 4 + 2] = v.z; pr[q * 4 + 3] = v.w;
                }
                const float4* eb4 = (const float4*)(embS + cl * 1032);
                const float* e2 = e2S + cl * 64;
                float best = 1e30f, second = 1e30f;
                int bp = 0;
                for (int p = 0; p < 64; ++p) {
                    const float4 e0 = eb4[p * 4 + 0], e1 = eb4[p * 4 + 1];
                    const float4 e2v = eb4[p * 4 + 2], e3 = eb4[p * 4 + 3];
                    float s = 0.f;
                    s = fmaf(pr[0], e0.x, s);   s = fmaf(pr[1], e0.y, s);
                    s = fmaf(pr[2], e0.z, s);   s = fmaf(pr[3], e0.w, s);
                    s = fmaf(pr[4], e1.x, s);   s = fmaf(pr[5], e1.y, s);
                    s = fmaf(pr[6], e1.z, s);   s = fmaf(pr[7], e1.w, s);
                    s = fmaf(pr[8], e2v.x, s);  s = fmaf(pr[9], e2v.y, s);
                    s = fmaf(pr[10], e2v.z, s); s = fmaf(pr[11], e2v.w, s);
                    s = fmaf(pr[12], e3.x, s);  s = fmaf(pr[13], e3.y, s);
                    s = fmaf(pr[14], e3.z, s);  s = fmaf(pr[15], e3.w, s);
                    const float g = fmaf(-2.f, s, e2[p]);
                    if (g < best) { second = best; best = g; bp = p; }
                    else if (g < second) { second = g; }
                }
                const int c = cbase + ch * 4 + cl;
                const int gtok = tb * 128 + h * 64 + lt;
                idxbuf[(set * NC + c) * NTOK + gtok] = bp;
                if (second - best < MARGIN) {
                    const int slot = atomicAdd(cnt, 1);
                    if (slot < LCAP) list[slot] = (set << 19) | (c << 13) | gtok;
                }
            }
        }
    }
}

// ------------------------------------------------------------------
// Kernel 2: fp64 exact re-resolution of flagged near-tie argmins.
// ------------------------------------------------------------------
__global__ __launch_bounds__(256) void k_refine(
    const float* __restrict__ x,
    const float* __restrict__ W_A, const float* __restrict__ W_B,
    const float* __restrict__ emb_A, const float* __restrict__ emb_B,
    const int* __restrict__ list, const int* __restrict__ cnt,
    int* __restrict__ idxbuf)
{
    int n = *cnt;
    if (n > LCAP) n = LCAP;
    const int lane = threadIdx.x & 63;
    const int wave = (int)((blockIdx.x * blockDim.x + threadIdx.x) >> 6);
    const int nw   = (int)((gridDim.x * blockDim.x) >> 6);

    for (int i = wave; i < n; i += nw) {
        const int code = list[i];
        const int tok = code & 8191;
        const int c   = (code >> 13) & 63;
        const int set = (code >> 19) & 1;
        const float* __restrict__ Wp = set ? W_B : W_A;
        const float* __restrict__ Ep = set ? emb_B : emb_A;

        double pk[16];
        #pragma unroll
        for (int k = 0; k < 16; ++k) pk[k] = 0.0;
        for (int dd = 0; dd < 16; ++dd) {
            const int d = dd * 64 + lane;
            const double xv = (double)x[(size_t)tok * DMODEL + d];
            #pragma unroll
            for (int k = 0; k < 16; ++k)
                pk[k] = fma(xv, (double)Wp[(size_t)(c * 16 + k) * DMODEL + d], pk[k]);
        }
        #pragma unroll
        for (int k = 0; k < 16; ++k) {
            #pragma unroll
            for (int off = 32; off; off >>= 1)
                pk[k] += __shfl_xor(pk[k], off, 64);
        }
        double d2 = 0.0;
        #pragma unroll
        for (int k = 0; k < 16; ++k) {
            const double t = pk[k] - (double)Ep[(size_t)(c * NP + lane) * NK + k];
            d2 = fma(t, t, d2);
        }
        int bp = lane;
        double bv = d2;
        #pragma unroll
        for (int off = 32; off; off >>= 1) {
            const double ov = __shfl_xor(bv, off, 64);
            const int    op = __shfl_xor(bp, off, 64);
            if (ov < bv || (ov == bv && op < bp)) { bv = ov; bp = op; }
        }
        if (lane == 0) idxbuf[(set * NC + c) * NTOK + tok] = bp;
    }
}

// ------------------------------------------------------------------
// Kernel 3: per-token gather + t[r] + out[d]. One block per token.
// ------------------------------------------------------------------
__global__ __launch_bounds__(256) void k_combine(
    const float* __restrict__ x,
    const float* __restrict__ vals_A, const float* __restrict__ vals_B,
    const int* __restrict__ idxbuf, float* __restrict__ out)
{
    __shared__ float xsh[1032];
    __shared__ float part[256];
    __shared__ float tsh[8];
    __shared__ int sIA[64];
    __shared__ int sIB[64];

    const int tid = threadIdx.x;
    const int tok = blockIdx.x;

    if (tid < 64) {
        sIA[tid] = idxbuf[tid * NTOK + tok];
        sIB[tid] = idxbuf[(NC + tid) * NTOK + tok];
    }
    {
        const float4 v = *(const float4*)(x + (size_t)tok * DMODEL + tid * 4);
        const int base = tid * 4 + (tid >> 5);
        xsh[base + 0] = v.x;
        xsh[base + 1] = v.y;
        xsh[base + 2] = v.z;
        xsh[base + 3] = v.w;
    }
    __syncthreads();
    {
        const int c = tid & 63, mseg = tid >> 6;
        const int ia = sIA[c];
        const float4* va = (const float4*)(vals_A + (size_t)(c * NP + ia) * NM + mseg * 32);
        const float* xb = xsh + (c & 7) * 129 + mseg * 32;
        float s = 0.f;
        #pragma unroll
        for (int i = 0; i < 8; ++i) {
            const float4 v = va[i];
            s = fmaf(v.x, xb[i * 4 + 0], s);
            s = fmaf(v.y, xb[i * 4 + 1], s);
            s = fmaf(v.z, xb[i * 4 + 2], s);
            s = fmaf(v.w, xb[i * 4 + 3], s);
        }
        part[tid] = s;
    }
    __syncthreads();
    if (tid < 8) {
        float s = 0.f;
        #pragma unroll
        for (int m = 0; m < 4; ++m)
            #pragma unroll
            for (int j = 0; j < 8; ++j)
                s += part[m * 64 + tid * 8 + j];
        tsh[tid] = s;
    }
    __syncthreads();
    {
        const int d0 = tid * 4, dblk = tid >> 5, dm = d0 & 127;
        float o0 = 0.f, o1 = 0.f, o2 = 0.f, o3 = 0.f;
        #pragma unroll
        for (int r = 0; r < 8; ++r) {
            const int cb = 8 * r + dblk;
            const int ib = sIB[cb];
            const float4 v = *(const float4*)(vals_B + (size_t)(cb * NP + ib) * NM + dm);
            const float tv = tsh[r];
            o0 = fmaf(tv, v.x, o0);
            o1 = fmaf(tv, v.y, o1);
            o2 = fmaf(tv, v.z, o2);
            o3 = fmaf(tv, v.w, o3);
        }
        *(float4*)(out + (size_t)tok * DMODEL + d0) = make_float4(o0, o1, o2, o3);
    }
}

extern "C" void kernel_launch(void* const* d_in, const int* in_sizes, int n_in,
                              void* d_out, int out_size, void* d_ws, size_t ws_size,
                              hipStream_t stream)
{
    const float* x      = (const float*)d_in[0];
    const float* W_A    = (const float*)d_in[1];
    const float* emb_A  = (const float*)d_in[2];
    const float* vals_A = (const float*)d_in[3];
    const float* W_B    = (const float*)d_in[4];
    const float* emb_B  = (const float*)d_in[5];
    const float* vals_B = (const float*)d_in[6];
    float* out = (float*)d_out;

    // ws: cnt 16B | list 1MB | idxbuf 4MB | xh 16MB | xl 16MB | whA/wlA/whB/wlB 4MB each
    char* w = (char*)d_ws;
    int*   cnt    = (int*)w;
    int*   list   = (int*)(w + 16);
    int*   idxbuf = (int*)(w + 16 + sizeof(int) * (size_t)LCAP);
    size_t off = 16 + sizeof(int) * (size_t)LCAP + sizeof(int) * (size_t)(2 * NC * NTOK);
    short* xh  = (short*)(w + off); off += (size_t)NTOK * DMODEL * 2;
    short* xl  = (short*)(w + off); off += (size_t)NTOK * DMODEL * 2;
    short* whA = (short*)(w + off); off += (size_t)1024 * DMODEL * 2;
    short* wlA = (short*)(w + off); off += (size_t)1024 * DMODEL * 2;
    short* whB = (short*)(w + off); off += (size_t)1024 * DMODEL * 2;
    short* wlB = (short*)(w + off);

    hipMemsetAsync(cnt, 0, sizeof(int), stream);
    k_split<<<5120, 256, 0, stream>>>(x, W_A, W_B, xh, xl, whA, wlA, whB, wlB);
    k_mfma_argmin<<<1024, 256, 0, stream>>>(xh, xl, whA, wlA, whB, wlB,
                                            emb_A, emb_B, idxbuf, list, cnt);
    k_refine<<<1024, 256, 0, stream>>>(x, W_A, W_B, emb_A, emb_B, list, cnt, idxbuf);
    k_combine<<<NTOK, 256, 0, stream>>>(x, vals_A, vals_B, idxbuf, out);
}